// Round 5
// baseline (638.048 us; speedup 1.0000x reference)
//
#include <hip/hip_runtime.h>

#define D 128
#define NSLICE 8

typedef int   vint4   __attribute__((ext_vector_type(4)));
typedef float vfloat4 __attribute__((ext_vector_type(4)));

// ---------------- setup: transpose weights + fold Wc = Vkx - 2*Wkx ----------------
__global__ __launch_bounds__(256) void setup_weights(
    const float* __restrict__ Uky, const float* __restrict__ Ukx,
    const float* __restrict__ Vky, const float* __restrict__ Vkx,
    const float* __restrict__ Wkx, const float* __restrict__ Vkx_b,
    const float* __restrict__ Wkx_b,
    float* __restrict__ UkyT, float* __restrict__ UkxT,
    float* __restrict__ VkyT, float* __restrict__ WcT, float* __restrict__ bc)
{
    const int m = blockIdx.x;
    const float* src = (m == 0) ? Uky : (m == 1) ? Ukx : (m == 2) ? Vky : nullptr;
    float* dst = (m == 0) ? UkyT : (m == 1) ? UkxT : (m == 2) ? VkyT : WcT;
    for (int i = threadIdx.x; i < D * D; i += 256) {
        int k = i >> 7, d = i & 127;
        float v;
        if (m == 3) v = Vkx[d * D + k] - 2.0f * Wkx[d * D + k];
        else        v = src[d * D + k];
        dst[i] = v;
    }
    if (m == 3 && threadIdx.x < D)
        bc[threadIdx.x] = Vkx_b[threadIdx.x] - 2.0f * Wkx_b[threadIdx.x];
}

// ---------------- fused GEMM v2 (pre-transposed W) ----------------
template <int EPI>
__global__ __launch_bounds__(256) void gemm_v2(
    const float* __restrict__ X, const float* __restrict__ WT,
    const float* __restrict__ bias, const float* __restrict__ colvec,
    const float* __restrict__ spout, const float* __restrict__ scal,
    float* __restrict__ out, int N)
{
    __shared__ float Xs[64][D + 4];
    __shared__ float Wt[64][D + 4];
    const int t = threadIdx.x;
    const int block_row = blockIdx.x * 64;

#pragma unroll
    for (int i = 0; i < 8; ++i) {
        int f = t + i * 256;
        int r = f >> 5;
        int k4 = (f & 31) << 2;
        float4 g = make_float4(0.f, 0.f, 0.f, 0.f);
        int row = block_row + r;
        if (row < N) g = *reinterpret_cast<const float4*>(&X[(size_t)row * D + k4]);
        *reinterpret_cast<float4*>(&Xs[r][k4]) = g;
    }

    const int cg = t & 15;
    const int rp = t >> 4;
    const int r0 = rp * 4;
    const int c0 = cg * 4, c1 = 64 + cg * 4;

    float acc[4][8] = {{0.f}};

    for (int kb = 0; kb < D; kb += 64) {
        __syncthreads();
#pragma unroll
        for (int i = 0; i < 8; ++i) {
            int f = t + i * 256;
            int kk = f >> 5;
            int d4 = (f & 31) << 2;
            float4 g = *reinterpret_cast<const float4*>(&WT[(size_t)(kb + kk) * D + d4]);
            *reinterpret_cast<float4*>(&Wt[kk][d4]) = g;
        }
        __syncthreads();
#pragma unroll 2
        for (int k4 = 0; k4 < 64; k4 += 4) {
            float4 xr[4];
#pragma unroll
            for (int j = 0; j < 4; ++j)
                xr[j] = *reinterpret_cast<const float4*>(&Xs[r0 + j][kb + k4]);
#pragma unroll
            for (int q = 0; q < 4; ++q) {
                const float4 w0 = *reinterpret_cast<const float4*>(&Wt[k4 + q][c0]);
                const float4 w1 = *reinterpret_cast<const float4*>(&Wt[k4 + q][c1]);
#pragma unroll
                for (int j = 0; j < 4; ++j) {
                    const float xv = (q == 0) ? xr[j].x : (q == 1) ? xr[j].y
                                   : (q == 2) ? xr[j].z : xr[j].w;
                    acc[j][0] += xv * w0.x; acc[j][1] += xv * w0.y;
                    acc[j][2] += xv * w0.z; acc[j][3] += xv * w0.w;
                    acc[j][4] += xv * w1.x; acc[j][5] += xv * w1.y;
                    acc[j][6] += xv * w1.z; acc[j][7] += xv * w1.w;
                }
            }
        }
    }

    const float sc = (EPI == 0) ? 0.f : scal[0];
    const float4 bias0 = *reinterpret_cast<const float4*>(&bias[c0]);
    const float4 bias1 = *reinterpret_cast<const float4*>(&bias[c1]);

#pragma unroll
    for (int j = 0; j < 4; ++j) {
        const int row = block_row + r0 + j;
        if (row >= N) continue;
        const float cv = (EPI == 0) ? 0.f : colvec[row];
#pragma unroll
        for (int h = 0; h < 2; ++h) {
            const int col = (h == 0) ? c0 : c1;
            const float4 bs = (h == 0) ? bias0 : bias1;
            float4 res;
            res.x = acc[j][h * 4 + 0] + bs.x;
            res.y = acc[j][h * 4 + 1] + bs.y;
            res.z = acc[j][h * 4 + 2] + bs.z;
            res.w = acc[j][h * 4 + 3] + bs.w;
            if (EPI == 1) {
                float4 sp = *reinterpret_cast<const float4*>(&spout[(size_t)row * D + col]);
                res.x = fmaxf(res.x - sc * (cv - sp.x), 0.f);
                res.y = fmaxf(res.y - sc * (cv - sp.y), 0.f);
                res.z = fmaxf(res.z - sc * (cv - sp.z), 0.f);
                res.w = fmaxf(res.w - sc * (cv - sp.w), 0.f);
            } else if (EPI == 2) {
                float4 sp = *reinterpret_cast<const float4*>(&spout[(size_t)row * D + col]);
                res.x = fmaxf(res.x - sc * (cv + sp.x), 0.f);
                res.y = fmaxf(res.y - sc * (cv + sp.y), 0.f);
                res.z = fmaxf(res.z - sc * (cv + sp.z), 0.f);
                res.w = fmaxf(res.w - sc * (cv + sp.w), 0.f);
            }
            *reinterpret_cast<float4*>(&out[(size_t)row * D + col]) = res;
        }
    }
}

// ---------------- CSR build ----------------
__global__ __launch_bounds__(256) void hist_both(const int* __restrict__ rows,
                                                 const int* __restrict__ cols,
                                                 int* __restrict__ cntR,
                                                 int* __restrict__ cntC, int nnz) {
    int e = blockIdx.x * 256 + threadIdx.x;
    if (e < nnz) {
        atomicAdd(&cntR[__builtin_nontemporal_load(&rows[e])], 1);
        atomicAdd(&cntC[__builtin_nontemporal_load(&cols[e])], 1);
    }
}

__global__ __launch_bounds__(256) void scan_block2(
    const int* __restrict__ in0, int* __restrict__ out0, int* __restrict__ bs0,
    const int* __restrict__ in1, int* __restrict__ out1, int* __restrict__ bs1, int n)
{
    const int* in = blockIdx.y ? in1 : in0;
    int* out = blockIdx.y ? out1 : out0;
    int* bs  = blockIdx.y ? bs1 : bs0;
    __shared__ int s[256];
    int i = blockIdx.x * 256 + threadIdx.x;
    int v = (i < n) ? in[i] : 0;
    s[threadIdx.x] = v;
    __syncthreads();
#pragma unroll
    for (int d = 1; d < 256; d <<= 1) {
        int tv = (threadIdx.x >= d) ? s[threadIdx.x - d] : 0;
        __syncthreads();
        s[threadIdx.x] += tv;
        __syncthreads();
    }
    if (i < n) out[i] = s[threadIdx.x] - v;
    if (threadIdx.x == 255) bs[blockIdx.x] = s[255];
}

__global__ __launch_bounds__(256) void scan_bsum2(int* __restrict__ bs0,
                                                  int* __restrict__ bs1, int nb) {
    int* bs = blockIdx.x ? bs1 : bs0;
    __shared__ int s[256];
    int v = (threadIdx.x < nb) ? bs[threadIdx.x] : 0;
    s[threadIdx.x] = v;
    __syncthreads();
#pragma unroll
    for (int d = 1; d < 256; d <<= 1) {
        int tv = (threadIdx.x >= d) ? s[threadIdx.x - d] : 0;
        __syncthreads();
        s[threadIdx.x] += tv;
        __syncthreads();
    }
    if (threadIdx.x < nb) bs[threadIdx.x] = s[threadIdx.x] - v;
}

__global__ __launch_bounds__(256) void add_bsum2(int* __restrict__ o0, int* __restrict__ o1,
                                                 const int* __restrict__ bs0,
                                                 const int* __restrict__ bs1, int n) {
    int* o = blockIdx.y ? o1 : o0;
    const int* bs = blockIdx.y ? bs1 : bs0;
    int i = blockIdx.x * 256 + threadIdx.x;
    if (i < n) o[i] += bs[blockIdx.x];
}

// ---------------- destination-sliced scatter with NT streaming loads ----------------
// Slice s only commits records with destination in its N/8 window (3.2 MB, L2-local
// via round-robin block->XCD). NT loads keep the 19.2 MB edge stream from evicting
// the dirty pair-window lines before they're fully assembled.
__global__ __launch_bounds__(256) void scatter_sliced(
    const int* __restrict__ rows, const int* __restrict__ cols,
    const float* __restrict__ vals,
    const int* __restrict__ offR, int* __restrict__ cR2, int2* __restrict__ pairsR,
    const int* __restrict__ offC, int* __restrict__ cC2, int2* __restrict__ pairsC,
    int nnz, int N, int ce)
{
    const int slice  = blockIdx.x & (NSLICE - 1);
    const int chunk  = blockIdx.x >> 3;
    const int rps    = (N + NSLICE - 1) / NSLICE;
    const int lo     = slice * rps;
    const int hi     = min(N, lo + rps);
    const int e0     = chunk * ce;
    const int e1     = min(nnz, e0 + ce);

    for (int eb = e0 + threadIdx.x * 4; eb < e1; eb += 256 * 4) {
        int rr[4], cc[4];
        float vv[4];
        if (eb + 3 < e1) {
            vint4 r4 = __builtin_nontemporal_load(reinterpret_cast<const vint4*>(&rows[eb]));
            vint4 c4 = __builtin_nontemporal_load(reinterpret_cast<const vint4*>(&cols[eb]));
            vfloat4 v4 = __builtin_nontemporal_load(reinterpret_cast<const vfloat4*>(&vals[eb]));
            rr[0] = r4.x; rr[1] = r4.y; rr[2] = r4.z; rr[3] = r4.w;
            cc[0] = c4.x; cc[1] = c4.y; cc[2] = c4.z; cc[3] = c4.w;
            vv[0] = v4.x; vv[1] = v4.y; vv[2] = v4.z; vv[3] = v4.w;
        } else {
#pragma unroll
            for (int u = 0; u < 4; ++u) {
                int e = eb + u;
                rr[u] = (e < e1) ? rows[e] : -1;
                cc[u] = (e < e1) ? cols[e] : -1;
                vv[u] = (e < e1) ? vals[e] : 0.f;
            }
        }
#pragma unroll
        for (int u = 0; u < 4; ++u) {
            int r = rr[u], c = cc[u];
            int vbits = __float_as_int(vv[u]);
            if (r >= lo && r < hi) {
                int p = offR[r] + atomicAdd(&cR2[r], 1);
                pairsR[p] = make_int2(c, vbits);
            }
            if (c >= lo && c < hi) {
                int p = offC[c] + atomicAdd(&cC2[c], 1);
                pairsC[p] = make_int2(r, vbits);
            }
        }
    }
}

// ---------------- pairs-gather SpMM v2: half-wave float4, 8 edges in flight ----------
__global__ __launch_bounds__(256) void spmm_pairs_v2(
    const int2* __restrict__ pairs, const int* __restrict__ off,
    const int* __restrict__ len, const float* __restrict__ X,
    float* __restrict__ out, int N)
{
    const int row = (blockIdx.x * 256 + threadIdx.x) >> 6;
    if (row >= N) return;
    const int lane = threadIdx.x & 63;
    const int half = lane >> 5;        // halves handle alternating edges
    const int cq = (lane & 31) << 2;   // float4 column chunk
    const int s = off[row];
    const int L = len[row];

    float4 a0 = make_float4(0.f, 0.f, 0.f, 0.f);
    float4 a1 = make_float4(0.f, 0.f, 0.f, 0.f);
    float4 a2 = make_float4(0.f, 0.f, 0.f, 0.f);
    float4 a3 = make_float4(0.f, 0.f, 0.f, 0.f);

    int i = 0;
    for (; i + 7 < L; i += 8) {
        int2 p0 = pairs[s + i + 0 + half];
        int2 p1 = pairs[s + i + 2 + half];
        int2 p2 = pairs[s + i + 4 + half];
        int2 p3 = pairs[s + i + 6 + half];
        float4 x0 = *reinterpret_cast<const float4*>(&X[(size_t)p0.x * D + cq]);
        float4 x1 = *reinterpret_cast<const float4*>(&X[(size_t)p1.x * D + cq]);
        float4 x2 = *reinterpret_cast<const float4*>(&X[(size_t)p2.x * D + cq]);
        float4 x3 = *reinterpret_cast<const float4*>(&X[(size_t)p3.x * D + cq]);
        float v0 = __int_as_float(p0.y), v1 = __int_as_float(p1.y);
        float v2 = __int_as_float(p2.y), v3 = __int_as_float(p3.y);
        a0.x += v0 * x0.x; a0.y += v0 * x0.y; a0.z += v0 * x0.z; a0.w += v0 * x0.w;
        a1.x += v1 * x1.x; a1.y += v1 * x1.y; a1.z += v1 * x1.z; a1.w += v1 * x1.w;
        a2.x += v2 * x2.x; a2.y += v2 * x2.y; a2.z += v2 * x2.z; a2.w += v2 * x2.w;
        a3.x += v3 * x3.x; a3.y += v3 * x3.y; a3.z += v3 * x3.z; a3.w += v3 * x3.w;
    }
    for (; i < L; i += 2) {
        int e = i + half;
        int2 p = (e < L) ? pairs[s + e] : make_int2(0, 0);   // v=0 when OOB
        float v = __int_as_float(p.y);
        float4 xv = *reinterpret_cast<const float4*>(&X[(size_t)p.x * D + cq]);
        a0.x += v * xv.x; a0.y += v * xv.y; a0.z += v * xv.z; a0.w += v * xv.w;
    }

    float4 A;
    A.x = (a0.x + a1.x) + (a2.x + a3.x);
    A.y = (a0.y + a1.y) + (a2.y + a3.y);
    A.z = (a0.z + a1.z) + (a2.z + a3.z);
    A.w = (a0.w + a1.w) + (a2.w + a3.w);
    A.x += __shfl_xor(A.x, 32);
    A.y += __shfl_xor(A.y, 32);
    A.z += __shfl_xor(A.z, 32);
    A.w += __shfl_xor(A.w, 32);
    if (half == 0)
        *reinterpret_cast<float4*>(&out[(size_t)row * D + cq]) = A;
}

// ---------------- fallback kernels ----------------
__global__ __launch_bounds__(256) void hist_kernel(const int* __restrict__ orow,
                                                   int* __restrict__ cnt, int nnz) {
    int e = blockIdx.x * 256 + threadIdx.x;
    if (e < nnz) atomicAdd(&cnt[orow[e]], 1);
}

__global__ __launch_bounds__(256) void scatter_kernel(const int* __restrict__ orow,
                                                      const int* __restrict__ off,
                                                      int* __restrict__ cnt2,
                                                      int* __restrict__ perm, int nnz) {
    int e = blockIdx.x * 256 + threadIdx.x;
    if (e < nnz) {
        int r = orow[e];
        int p = off[r] + atomicAdd(&cnt2[r], 1);
        perm[p] = e;
    }
}

__global__ __launch_bounds__(256) void spmm_gather(
    const float* __restrict__ vals, const int* __restrict__ gcol,
    const int* __restrict__ perm, const int* __restrict__ off,
    const int* __restrict__ len, const float* __restrict__ X,
    float* __restrict__ out, int N)
{
    const int row = (blockIdx.x * 256 + threadIdx.x) >> 6;
    if (row >= N) return;
    const int lane = threadIdx.x & 63;
    const int s = off[row];
    const int L = len[row];
    float ax = 0.f, ay = 0.f, bx = 0.f, by = 0.f;
    int i = 0;
    for (; i + 1 < L; i += 2) {
        int e0 = perm[s + i];
        int e1 = perm[s + i + 1];
        float v0 = vals[e0];
        float v1 = vals[e1];
        int c0 = gcol[e0];
        int c1 = gcol[e1];
        float2 x0 = *reinterpret_cast<const float2*>(&X[(size_t)c0 * D + lane * 2]);
        float2 x1 = *reinterpret_cast<const float2*>(&X[(size_t)c1 * D + lane * 2]);
        ax += v0 * x0.x; ay += v0 * x0.y;
        bx += v1 * x1.x; by += v1 * x1.y;
    }
    if (i < L) {
        int e0 = perm[s + i];
        float v0 = vals[e0];
        int c0 = gcol[e0];
        float2 x0 = *reinterpret_cast<const float2*>(&X[(size_t)c0 * D + lane * 2]);
        ax += v0 * x0.x; ay += v0 * x0.y;
    }
    *reinterpret_cast<float2*>(&out[(size_t)row * D + lane * 2]) =
        make_float2(ax + bx, ay + by);
}

__global__ __launch_bounds__(256) void spmm_atomic(
    const float* __restrict__ vals, const int* __restrict__ orow,
    const int* __restrict__ gcol, const float* __restrict__ Xm,
    float* __restrict__ outm, int nnz)
{
    const int gwave = (blockIdx.x * 256 + threadIdx.x) >> 6;
    const int lane = threadIdx.x & 63;
    const int e0 = gwave * 4;
#pragma unroll
    for (int i = 0; i < 4; ++i) {
        int e = e0 + i;
        if (e >= nnz) break;
        float v = vals[e];
        int r = orow[e];
        int c = gcol[e];
        float2 xv = *reinterpret_cast<const float2*>(&Xm[(size_t)c * D + lane * 2]);
        unsafeAtomicAdd(&outm[(size_t)r * D + lane * 2 + 0], v * xv.x);
        unsafeAtomicAdd(&outm[(size_t)r * D + lane * 2 + 1], v * xv.y);
    }
}

extern "C" void kernel_launch(void* const* d_in, const int* in_sizes, int n_in,
                              void* d_out, int out_size, void* d_ws, size_t ws_size,
                              hipStream_t stream) {
    const float* x      = (const float*)d_in[0];
    const float* y      = (const float*)d_in[1];
    const float* c      = (const float*)d_in[2];
    const float* b      = (const float*)d_in[3];
    const float* A_vals = (const float*)d_in[4];
    const int*   A_rows = (const int*)d_in[5];
    const int*   A_cols = (const int*)d_in[6];
    const float* Ukx_w  = (const float*)d_in[7];
    const float* Ukx_b  = (const float*)d_in[8];
    const float* Uky_w  = (const float*)d_in[9];
    const float* Uky_b  = (const float*)d_in[10];
    const float* tau    = (const float*)d_in[11];
    const float* Vky_w  = (const float*)d_in[12];
    const float* Vky_b  = (const float*)d_in[13];
    const float* Wkx_w  = (const float*)d_in[14];
    const float* Wkx_b  = (const float*)d_in[15];
    const float* Vkx_w  = (const float*)d_in[16];
    const float* Vkx_b  = (const float*)d_in[17];
    const float* sigma  = (const float*)d_in[18];

    const int N   = in_sizes[0] / D;   // 50000
    const int nnz = in_sizes[4];       // 1.6M
    const int nb  = (N + 255) / 256;

    float* out_x = (float*)d_out;
    float* out_y = out_x + (size_t)N * D;

    const int gemm_grid = (N + 63) / 64;
    const int egrid = (nnz + 255) / 256;
    const int ggrid = (N + 3) / 4;

    float* tmp  = (float*)d_ws;
    float* UkyT = tmp + (size_t)N * D;
    float* UkxT = UkyT + D * D;
    float* VkyT = UkxT + D * D;
    float* WcT  = VkyT + D * D;
    float* bc   = WcT + D * D;
    int* cntR = (int*)(bc + D);
    int* cntC = cntR + N;
    int* cR2  = cntC + N;
    int* cC2  = cR2 + N;
    int* offR = cC2 + N;
    int* offC = offR + N;
    int* bsR  = offC + N;
    int* bsC  = bsR + 256;
    int2* pairsR = (int2*)(bsC + 256);
    int2* pairsC = pairsR + nnz;

    size_t needA = ((size_t)N * D + 4 * D * D + D + 6 * (size_t)N + 512 + 4 * (size_t)nnz) * 4;
    size_t needB = ((size_t)N * D + 4 * D * D + D + 3 * (size_t)N + 256 + (size_t)nnz) * 4;

    setup_weights<<<4, 256, 0, stream>>>(Uky_w, Ukx_w, Vky_w, Vkx_w, Wkx_w,
                                         Vkx_b, Wkx_b, UkyT, UkxT, VkyT, WcT, bc);

    if (ws_size >= needA && nb <= 256) {
        // ---- CSR build ----
        hipMemsetAsync(cntR, 0, 4 * (size_t)N * sizeof(int), stream);
        hist_both<<<egrid, 256, 0, stream>>>(A_rows, A_cols, cntR, cntC, nnz);
        {
            dim3 g(nb, 2);
            scan_block2<<<g, 256, 0, stream>>>(cntR, offR, bsR, cntC, offC, bsC, N);
            scan_bsum2<<<2, 256, 0, stream>>>(bsR, bsC, nb);
            add_bsum2<<<g, 256, 0, stream>>>(offR, offC, bsR, bsC, N);
        }
        {
            const int NCHUNK = 128;
            int ce = ((nnz + NCHUNK - 1) / NCHUNK + 3) & ~3;
            scatter_sliced<<<NSLICE * NCHUNK, 256, 0, stream>>>(
                A_rows, A_cols, A_vals, offR, cR2, pairsR, offC, cC2, pairsC, nnz, N, ce);
        }

        // uy = y @ Uky^T + b  -> staged in out_y
        gemm_v2<0><<<gemm_grid, 256, 0, stream>>>(y, UkyT, Uky_b, nullptr, nullptr, nullptr, out_y, N);
        // at_uy -> out_x
        spmm_pairs_v2<<<ggrid, 256, 0, stream>>>(pairsC, offC, cntC, out_y, out_x, N);
        // x_new -> out_x (in place)
        gemm_v2<1><<<gemm_grid, 256, 0, stream>>>(x, UkxT, Ukx_b, c, out_x, tau, out_x, N);
        // zx -> tmp
        gemm_v2<0><<<gemm_grid, 256, 0, stream>>>(out_x, WcT, bc, nullptr, nullptr, nullptr, tmp, N);
        // az -> out_y
        spmm_pairs_v2<<<ggrid, 256, 0, stream>>>(pairsR, offR, cntR, tmp, out_y, N);
        // y_new -> out_y (in place)
        gemm_v2<2><<<gemm_grid, 256, 0, stream>>>(y, VkyT, Vky_b, b, out_y, sigma, out_y, N);
    } else if (ws_size >= needB && nb <= 256) {
        // ---- perm path ----
        int* cnt  = (int*)(bc + D);
        int* cnt2 = cnt + N;
        int* off  = cnt2 + N;
        int* bsum = off + N;
        int* perm = bsum + 256;
        dim3 g1(nb, 1);

        gemm_v2<0><<<gemm_grid, 256, 0, stream>>>(y, UkyT, Uky_b, nullptr, nullptr, nullptr, out_y, N);

        hipMemsetAsync(cnt, 0, 2 * (size_t)N * sizeof(int), stream);
        hist_kernel<<<egrid, 256, 0, stream>>>(A_cols, cnt, nnz);
        scan_block2<<<g1, 256, 0, stream>>>(cnt, off, bsum, cnt, off, bsum, N);
        scan_bsum2<<<1, 256, 0, stream>>>(bsum, bsum, nb);
        add_bsum2<<<g1, 256, 0, stream>>>(off, off, bsum, bsum, N);
        scatter_kernel<<<egrid, 256, 0, stream>>>(A_cols, off, cnt2, perm, nnz);
        spmm_gather<<<ggrid, 256, 0, stream>>>(A_vals, A_rows, perm, off, cnt, out_y, out_x, N);

        gemm_v2<1><<<gemm_grid, 256, 0, stream>>>(x, UkxT, Ukx_b, c, out_x, tau, out_x, N);
        gemm_v2<0><<<gemm_grid, 256, 0, stream>>>(out_x, WcT, bc, nullptr, nullptr, nullptr, tmp, N);

        hipMemsetAsync(cnt, 0, 2 * (size_t)N * sizeof(int), stream);
        hist_kernel<<<egrid, 256, 0, stream>>>(A_rows, cnt, nnz);
        scan_block2<<<g1, 256, 0, stream>>>(cnt, off, bsum, cnt, off, bsum, N);
        scan_bsum2<<<1, 256, 0, stream>>>(bsum, bsum, nb);
        add_bsum2<<<g1, 256, 0, stream>>>(off, off, bsum, bsum, N);
        scatter_kernel<<<egrid, 256, 0, stream>>>(A_rows, off, cnt2, perm, nnz);
        spmm_gather<<<ggrid, 256, 0, stream>>>(A_vals, A_cols, perm, off, cnt, tmp, out_y, N);

        gemm_v2<2><<<gemm_grid, 256, 0, stream>>>(y, VkyT, Vky_b, b, out_y, sigma, out_y, N);
    } else {
        // ---- atomic fallback ----
        const int spmm_grid = (nnz + 15) / 16;
        gemm_v2<0><<<gemm_grid, 256, 0, stream>>>(y, UkyT, Uky_b, nullptr, nullptr, nullptr, tmp, N);
        hipMemsetAsync(out_x, 0, (size_t)N * D * sizeof(float), stream);
        spmm_atomic<<<spmm_grid, 256, 0, stream>>>(A_vals, A_cols, A_rows, tmp, out_x, nnz);
        gemm_v2<1><<<gemm_grid, 256, 0, stream>>>(x, UkxT, Ukx_b, c, out_x, tau, out_x, N);
        gemm_v2<0><<<gemm_grid, 256, 0, stream>>>(out_x, WcT, bc, nullptr, nullptr, nullptr, tmp, N);
        hipMemsetAsync(out_y, 0, (size_t)N * D * sizeof(float), stream);
        spmm_atomic<<<spmm_grid, 256, 0, stream>>>(A_vals, A_rows, A_cols, tmp, out_y, nnz);
        gemm_v2<2><<<gemm_grid, 256, 0, stream>>>(y, VkyT, Vky_b, b, out_y, sigma, out_y, N);
    }
}